// Round 10
// baseline (291.208 us; speedup 1.0000x reference)
//
#include <hip/hip_runtime.h>
#include <hip/hip_bf16.h>

#define CDIV(a,b) (((a)+(b)-1)/(b))
#define NBUCK_MAX 512   // buckets of 128 nodes; supports N up to 65536 (ebuf packing needs N<=65536)

typedef __attribute__((ext_vector_type(8))) short short8;
typedef __attribute__((ext_vector_type(4))) float f32x4;

static __device__ __forceinline__ unsigned short f2bf(float f){
  union { float f; unsigned u; } v; v.f = f;
  unsigned r = v.u + 0x7fffu + ((v.u >> 16) & 1u);   // RNE
  return (unsigned short)(r >> 16);
}
static __device__ __forceinline__ unsigned pack2(float lo, float hi){
  return (unsigned)f2bf(lo) | ((unsigned)f2bf(hi) << 16);
}
static __device__ __forceinline__ float bfu_lo(unsigned u){
  union { unsigned u; float f; } v; v.u = u << 16; return v.f;
}
static __device__ __forceinline__ float bfu_hi(unsigned u){
  union { unsigned u; float f; } v; v.u = u & 0xffff0000u; return v.f;
}
static __device__ __forceinline__ float bf2f(unsigned short s){
  union { unsigned u; float f; } v; v.u = ((unsigned)s) << 16; return v.f;
}

#define ACC8(v) { a0 += bfu_lo(v.x); a1 += bfu_hi(v.x); a2 += bfu_lo(v.y); a3 += bfu_hi(v.y); \
                  a4 += bfu_lo(v.z); a5 += bfu_hi(v.z); a6 += bfu_lo(v.w); a7 += bfu_hi(v.w); }

// ---------------- weight pack ----------------

struct WtpArgs {
  const float *W0, *W1, *bl, *g, *b, *rm, *rv;
  unsigned short* Bpk; float *sc; float *sh;
  int kblk, dout, do_bn, nblk;
};

static __device__ __forceinline__ void wtp_one(const WtpArgs& a, int idx){
  int NB16 = a.kblk*32*a.dout;
  if (idx < NB16){
    int j = idx & 7, lane = (idx >> 3) & 63, rest = idx >> 9;
    int NT = a.dout >> 4;
    int nt = rest % NT, kk = rest / NT;
    int nn = nt*16 + (lane & 15);
    int k  = kk*32 + ((lane >> 4) * 8) + j;
    float v = (k < 128) ? a.W0[nn*128 + k] : a.W1[nn*128 + (k - 128)];
    a.Bpk[idx] = f2bf(v);
  } else if (a.do_bn && idx < NB16 + a.dout){
    int jj = idx - NB16;
    float s = a.g[jj] * rsqrtf(a.rv[jj] + 1e-5f);
    a.sc[jj] = s;
    a.sh[jj] = (a.bl[jj] - a.rm[jj]) * s + a.b[jj];
  }
}

// ---------------- prep: cast x->bf16 | bucket histogram | weight pack, one launch ----------------

__global__ __launch_bounds__(256) void k_prep(const float* __restrict__ x, int n2, unsigned* __restrict__ xb,
                                              const int* __restrict__ dst, int E,
                                              int* __restrict__ bcnt, int nbuck,
                                              int castBlocks, int histBlocks,
                                              WtpArgs a0, WtpArgs a1, WtpArgs a2, WtpArgs a3){
  __shared__ int s[NBUCK_MAX];
  int b = blockIdx.x, t = threadIdx.x;
  if (b < castBlocks){
    int i = b*256 + t;
    if (i < n2){
      float2 v = ((const float2*)x)[i];
      xb[i] = pack2(v.x, v.y);
    }
    return;
  }
  b -= castBlocks;
  if (b < histBlocks){
    for (int i=t;i<nbuck;i+=256) s[i] = 0;
    __syncthreads();
    constexpr int EPT = 16;
    int e0 = b*256*EPT;
    #pragma unroll
    for (int i=0;i<EPT;i++){
      int e = e0 + i*256 + t;
      if (e < E) atomicAdd(&s[dst[e] >> 7], 1);
    }
    __syncthreads();
    for (int i=t;i<nbuck;i+=256){
      int c = s[i];
      if (c > 0) atomicAdd(&bcnt[i], c);
    }
    return;
  }
  b -= histBlocks;
  if (b < a0.nblk){ wtp_one(a0, b*256 + t); return; }
  b -= a0.nblk;
  if (b < a1.nblk){ wtp_one(a1, b*256 + t); return; }
  b -= a1.nblk;
  if (b < a2.nblk){ wtp_one(a2, b*256 + t); return; }
  b -= a2.nblk;
  wtp_one(a3, b*256 + t);
}

// Pass A: bin edges into 128-node buckets; local scan of bcnt replaces k_bscan.
// Packed entry (local_dst<<16)|src (N<=65536)
__global__ __launch_bounds__(256) void k_bucketA(const int* __restrict__ src, const int* __restrict__ dst,
                                                 int E, const int* __restrict__ bcnt,
                                                 int* __restrict__ bcur, unsigned* __restrict__ ebuf, int nbuck){
  __shared__ int scnt[NBUCK_MAX];
  __shared__ int sbase[NBUCK_MAX];
  __shared__ int sboff[NBUCK_MAX];
  __shared__ int sscan[256];
  int t = threadIdx.x;
  // local exclusive scan of bcnt -> sboff
  int p0 = (2*t   < nbuck) ? bcnt[2*t]   : 0;
  int p1 = (2*t+1 < nbuck) ? bcnt[2*t+1] : 0;
  sscan[t] = p0 + p1; __syncthreads();
  for (int d=1; d<256; d<<=1){
    int u = (t>=d) ? sscan[t-d] : 0;
    __syncthreads();
    sscan[t] += u;
    __syncthreads();
  }
  int excl = sscan[t] - (p0 + p1);
  if (2*t   < nbuck) sboff[2*t]   = excl;
  if (2*t+1 < nbuck) sboff[2*t+1] = excl + p0;
  for (int i=t;i<nbuck;i+=256) scnt[i] = 0;
  __syncthreads();

  constexpr int EPT = 16;
  int e0 = blockIdx.x*256*EPT;
  int b[EPT]; unsigned pk[EPT];
  #pragma unroll
  for (int i=0;i<EPT;i++){
    int e = e0 + i*256 + t;
    if (e < E){
      int d = dst[e];
      b[i] = d >> 7;
      pk[i] = ((unsigned)(d & 127) << 16) | (unsigned)src[e];
      atomicAdd(&scnt[b[i]], 1);
    } else b[i] = -1;
  }
  __syncthreads();
  for (int i=t;i<nbuck;i+=256){
    int c = scnt[i];
    sbase[i] = (c > 0) ? atomicAdd(&bcur[i], c) : 0;
    scnt[i] = 0;
  }
  __syncthreads();
  #pragma unroll
  for (int i=0;i<EPT;i++){
    if (b[i] >= 0){
      int p = atomicAdd(&scnt[b[i]], 1);
      ebuf[(size_t)sboff[b[i]] + sbase[b[i]] + p] = pk[i];
    }
  }
}

// Pass B: one block per bucket; local scan of bcnt + local degree count -> off + csr.
__global__ __launch_bounds__(256) void k_bucketB(const unsigned* __restrict__ ebuf, const int* __restrict__ bcnt,
                                                 int N, int* __restrict__ off, int* __restrict__ csr, int nbuck){
  __shared__ int sboff[NBUCK_MAX+1];
  __shared__ int sscan[256];
  __shared__ int sdeg[128];
  __shared__ int sabs[129];
  __shared__ int cur[128];
  int b = blockIdx.x, t = threadIdx.x;
  int n0 = b << 7, n1 = min(n0 + 128, N);
  // local exclusive scan of bcnt -> sboff[0..nbuck]
  int p0 = (2*t   < nbuck) ? bcnt[2*t]   : 0;
  int p1 = (2*t+1 < nbuck) ? bcnt[2*t+1] : 0;
  sscan[t] = p0 + p1; __syncthreads();
  for (int d=1; d<256; d<<=1){
    int u = (t>=d) ? sscan[t-d] : 0;
    __syncthreads();
    sscan[t] += u;
    __syncthreads();
  }
  int excl = sscan[t] - (p0 + p1);
  if (2*t   < nbuck) sboff[2*t]   = excl;
  if (2*t+1 < nbuck) sboff[2*t+1] = excl + p0;
  if (t == 255) sboff[nbuck] = sscan[255];
  if (t < 128){ sdeg[t] = 0; cur[t] = 0; }
  __syncthreads();
  int e0 = sboff[b], e1 = sboff[b+1];
  for (int e = e0 + t; e < e1; e += 256)
    atomicAdd(&sdeg[ebuf[e] >> 16], 1);
  __syncthreads();
  for (int d=1; d<128; d<<=1){
    int u = (t < 128 && t >= d) ? sdeg[t-d] : 0;
    __syncthreads();
    if (t < 128) sdeg[t] += u;
    __syncthreads();
  }
  if (t == 0) sabs[0] = e0;
  if (t < 128) sabs[t+1] = e0 + sdeg[t];
  __syncthreads();
  if (t <= n1 - n0) off[n0 + t] = sabs[t];
  for (int e = e0 + t; e < e1; e += 256){
    unsigned pr = ebuf[e];
    int ln = (int)(pr >> 16);
    int p = atomicAdd(&cur[ln], 1);
    csr[sabs[ln] + p] = (int)(pr & 0xffffu);
  }
}

// ---------------- fused hidden layer: mean gather (LDS tile) + dual-K GEMM + BN + ReLU ----------------
// Block owns 64 rows. Gather mean into Ms (padded stride 136); GEMM half1 A=Ms(LDS), half2 A=hin(global).
// If YL: yl = h @ Wl2^T (K=128, DOUT=64) -> outyl, A read back from just-written outh (same block; r8/r9-verified).

#define MSTRIDE 136

template<bool YL>
__global__ __launch_bounds__(256, 3) void k_fused(
    const unsigned short* __restrict__ hin, const int* __restrict__ off, const int* __restrict__ csr,
    const unsigned short* __restrict__ Bpk, const float* __restrict__ sc,
    const float* __restrict__ sh, const unsigned short* __restrict__ BpkL,
    unsigned short* __restrict__ outh, unsigned short* __restrict__ outyl, int n){
  __shared__ unsigned short Bs[128*128];     // 32 KB
  __shared__ unsigned short Ms[64*MSTRIDE];  // 17 KB padded mean tile
  int t = threadIdx.x;
  int lane = t & 63, w = t >> 6;
  int quad = lane >> 4, c = lane & 15;
  int sl = lane & 15;
  int mb = blockIdx.x*64;
  const uint4* hin4 = (const uint4*)hin;

  // stage Bs half 1 (overlaps with gather in MLP)
  {
    const uint4* s = (const uint4*)Bpk;
    uint4* d = (uint4*)Bs;
    #pragma unroll
    for (int i=0;i<8;i++) d[i*256 + t] = s[i*256 + t];
  }

  // gather phase: wave w covers local rows [w*16, w*16+16), one node per quad, 4 iterations
  #pragma unroll
  for (int it=0; it<4; it++){
    int ln = w*16 + it*4 + quad;
    int node = mb + ln;
    bool valid = node < n;
    int s0 = valid ? off[node]   : 0;
    int s1 = valid ? off[node+1] : 0;
    float a0=0,a1=0,a2=0,a3=0,a4=0,a5=0,a6=0,a7=0;
    int e = s0;
    for (; e + 16 <= s1; e += 16){
      uint4 v[16];
      #pragma unroll
      for (int i=0;i<16;i++) v[i] = hin4[(size_t)csr[e+i]*16 + sl];
      #pragma unroll
      for (int i=0;i<16;i++) ACC8(v[i]);
    }
    for (; e + 4 <= s1; e += 4){
      uint4 v[4];
      #pragma unroll
      for (int i=0;i<4;i++) v[i] = hin4[(size_t)csr[e+i]*16 + sl];
      #pragma unroll
      for (int i=0;i<4;i++) ACC8(v[i]);
    }
    for (; e < s1; e++){
      uint4 v = hin4[(size_t)csr[e]*16 + sl];
      ACC8(v);
    }
    int d = s1 - s0;
    float inv = 1.0f / (float)(d > 0 ? d : 1);
    uint4 o;
    o.x = pack2(a0*inv, a1*inv);
    o.y = pack2(a2*inv, a3*inv);
    o.z = pack2(a4*inv, a5*inv);
    o.w = pack2(a6*inv, a7*inv);
    *(uint4*)&Ms[ln*MSTRIDE + sl*8] = o;
  }
  __syncthreads();

  int r0 = mb + w*16 + c;
  int lr = w*16 + c;

  f32x4 acc[8];
  #pragma unroll
  for (int nt=0;nt<8;nt++) acc[nt] = (f32x4){0.f,0.f,0.f,0.f};

  // GEMM half 1: K=0..127, A = mean tile in LDS
  #pragma unroll
  for (int kk=0; kk<4; kk++){
    int ka = kk*32 + quad*8;
    short8 a0 = {0,0,0,0,0,0,0,0};
    if (r0 < n) a0 = *(const short8*)&Ms[lr*MSTRIDE + ka];
    #pragma unroll
    for (int nt=0; nt<8; nt++){
      short8 b = *(const short8*)&Bs[(size_t)((kk*8 + nt)*64 + lane)*8];
      acc[nt] = __builtin_amdgcn_mfma_f32_16x16x32_bf16(a0, b, acc[nt], 0, 0, 0);
    }
  }
  __syncthreads();
  // GEMM half 2: K=128..255, A = own rows from global
  {
    const uint4* s = (const uint4*)(Bpk + 16384);
    uint4* d = (uint4*)Bs;
    #pragma unroll
    for (int i=0;i<8;i++) d[i*256 + t] = s[i*256 + t];
  }
  __syncthreads();
  #pragma unroll
  for (int kk=0; kk<4; kk++){
    int ka = kk*32 + quad*8;
    short8 a0 = {0,0,0,0,0,0,0,0};
    if (r0 < n) a0 = *(const short8*)(hin + (size_t)r0*128 + ka);
    #pragma unroll
    for (int nt=0; nt<8; nt++){
      short8 b = *(const short8*)&Bs[(size_t)((kk*8 + nt)*64 + lane)*8];
      acc[nt] = __builtin_amdgcn_mfma_f32_16x16x32_bf16(a0, b, acc[nt], 0, 0, 0);
    }
  }

  float scv[8], shv[8];
  #pragma unroll
  for (int nt=0;nt<8;nt++){ scv[nt] = sc[nt*16 + c]; shv[nt] = sh[nt*16 + c]; }

  #pragma unroll
  for (int r=0;r<4;r++){
    int row = mb + w*16 + quad*4 + r;
    if (row < n){
      #pragma unroll
      for (int nt=0;nt<8;nt++){
        float u = acc[nt][r]*scv[nt] + shv[nt];
        u = fmaxf(u, 0.f);
        outh[(size_t)row*128 + nt*16 + c] = f2bf(u);
      }
    }
  }

  if constexpr (YL){
    __syncthreads();   // drain outh stores + finish Bs reads
    {
      const uint4* sL = (const uint4*)BpkL;
      uint4* d = (uint4*)Bs;
      #pragma unroll
      for (int i=0;i<4;i++) d[i*256 + t] = sL[i*256 + t];
    }
    __syncthreads();
    f32x4 acc2[4];
    #pragma unroll
    for (int nt=0;nt<4;nt++) acc2[nt] = (f32x4){0.f,0.f,0.f,0.f};
    int gr0 = r0 < n ? r0 : n-1;
    #pragma unroll
    for (int kk=0; kk<4; kk++){
      int ka = kk*32 + quad*8;
      short8 a0 = *(const short8*)(outh + (size_t)gr0*128 + ka);
      #pragma unroll
      for (int nt=0; nt<4; nt++){
        short8 b = *(const short8*)&Bs[(size_t)((kk*4 + nt)*64 + lane)*8];
        acc2[nt] = __builtin_amdgcn_mfma_f32_16x16x32_bf16(a0, b, acc2[nt], 0, 0, 0);
      }
    }
    #pragma unroll
    for (int r=0;r<4;r++){
      int row = mb + w*16 + quad*4 + r;
      if (row < n){
        #pragma unroll
        for (int nt=0;nt<4;nt++) outyl[(size_t)row*64 + nt*16 + c] = f2bf(acc2[nt][r]);
      }
    }
  }
}

// ---------------- fused layer-3: 64-row tile, mean-yl gather + GEMM + BN + L2norm ----------------

__global__ __launch_bounds__(256, 4) void k_aggf(
    const uint4* __restrict__ ylb4, const int* __restrict__ off, const int* __restrict__ csr,
    const unsigned short* __restrict__ A0, const unsigned short* __restrict__ BpkR,
    const float* __restrict__ sc, const float* __restrict__ sh,
    float* __restrict__ outf, int n){
  __shared__ unsigned short Ms[64*64];     // 8 KB mean-yl tile
  __shared__ unsigned short Bs[128*64];    // 16 KB BpkR
  int t = threadIdx.x;
  int lane = t & 63, w = t >> 6;
  int mb = blockIdx.x*64;
  int sl8 = lane & 7;
  {
    const uint4* s = (const uint4*)BpkR;
    uint4* d = (uint4*)Bs;
    #pragma unroll
    for (int i=0;i<4;i++) d[i*256 + t] = s[i*256 + t];
  }

  #pragma unroll
  for (int it=0; it<2; it++){
    int ln = w*16 + it*8 + (lane >> 3);
    int node = mb + ln;
    bool valid = node < n;
    int s0 = valid ? off[node]   : 0;
    int s1 = valid ? off[node+1] : 0;
    float a0=0,a1=0,a2=0,a3=0,a4=0,a5=0,a6=0,a7=0;
    int e = s0;
    for (; e + 4 <= s1; e += 4){
      uint4 v0 = ylb4[(size_t)csr[e  ]*8 + sl8];
      uint4 v1 = ylb4[(size_t)csr[e+1]*8 + sl8];
      uint4 v2 = ylb4[(size_t)csr[e+2]*8 + sl8];
      uint4 v3 = ylb4[(size_t)csr[e+3]*8 + sl8];
      ACC8(v0); ACC8(v1); ACC8(v2); ACC8(v3);
    }
    for (; e < s1; e++){
      uint4 v = ylb4[(size_t)csr[e]*8 + sl8];
      ACC8(v);
    }
    int d = s1 - s0;
    float inv = 1.0f / (float)(d > 0 ? d : 1);
    uint4 o;
    o.x = pack2(a0*inv, a1*inv);
    o.y = pack2(a2*inv, a3*inv);
    o.z = pack2(a4*inv, a5*inv);
    o.w = pack2(a6*inv, a7*inv);
    ((uint4*)Ms)[ln*8 + sl8] = o;
  }
  __syncthreads();

  int quad = lane >> 4, c = lane & 15;
  int r0 = mb + w*16 + c;
  f32x4 acc[4];
  #pragma unroll
  for (int nt=0;nt<4;nt++) acc[nt] = (f32x4){0.f,0.f,0.f,0.f};
  #pragma unroll
  for (int kk=0; kk<4; kk++){
    int ka = kk*32 + quad*8;
    short8 a0 = {0,0,0,0,0,0,0,0};
    if (r0 < n) a0 = *(const short8*)(A0 + (size_t)r0*128 + ka);
    #pragma unroll
    for (int nt=0; nt<4; nt++){
      short8 b = *(const short8*)&Bs[(size_t)((kk*4 + nt)*64 + lane)*8];
      acc[nt] = __builtin_amdgcn_mfma_f32_16x16x32_bf16(a0, b, acc[nt], 0, 0, 0);
    }
  }

  float scv[4], shv[4];
  #pragma unroll
  for (int nt=0;nt<4;nt++){ scv[nt] = sc[nt*16 + c]; shv[nt] = sh[nt*16 + c]; }

  #pragma unroll
  for (int r=0;r<4;r++){
    int lr = w*16 + quad*4 + r;
    int row = mb + lr;
    float v[4];
    float ss = 0.f;
    if (row < n){
      #pragma unroll
      for (int nt=0;nt<4;nt++){
        float u = acc[nt][r] + bf2f(Ms[lr*64 + nt*16 + c]);
        u = u*scv[nt] + shv[nt];
        v[nt] = u;
        ss += u*u;
      }
    } else {
      #pragma unroll
      for (int nt=0;nt<4;nt++) v[nt] = 0.f;
    }
    ss += __shfl_xor(ss, 1, 64);
    ss += __shfl_xor(ss, 2, 64);
    ss += __shfl_xor(ss, 4, 64);
    ss += __shfl_xor(ss, 8, 64);
    float rn = 1.0f / fmaxf(sqrtf(ss), 1e-12f);
    if (row < n){
      #pragma unroll
      for (int nt=0;nt<4;nt++) outf[(size_t)row*64 + nt*16 + c] = v[nt]*rn;
    }
  }
}

// ---------------- launcher ----------------

extern "C" void kernel_launch(void* const* d_in, const int* in_sizes, int n_in,
                              void* d_out, int out_size, void* d_ws, size_t ws_size,
                              hipStream_t stream){
  const float* x = (const float*)d_in[0];
  const int* ei  = (const int*)d_in[1];
  int N = in_sizes[0] / 128;
  int E = in_sizes[1] / 2;
  const int* esrc = ei;
  const int* edst = ei + E;
  int nbuck = CDIV(N, 128);

  const float *Wl[3], *bl[3], *Wr[3], *g[3], *bb[3], *rm[3], *rv[3];
  int dout[3];
  for (int i=0;i<3;i++){
    int base = 2 + 7*i;
    Wl[i]=(const float*)d_in[base];   bl[i]=(const float*)d_in[base+1];
    Wr[i]=(const float*)d_in[base+2]; g[i] =(const float*)d_in[base+3];
    bb[i]=(const float*)d_in[base+4]; rm[i]=(const float*)d_in[base+5];
    rv[i]=(const float*)d_in[base+6];
    dout[i] = in_sizes[base] / 128;
  }

  char* p = (char*)d_ws;
  size_t o = 0;
  auto alloc = [&](size_t bytes)->void*{ void* r = p + o; o += (bytes + 255) & ~(size_t)255; return r; };
  int* bz    = (int*)alloc((size_t)2*nbuck*4);   // bcnt | bcur (one memset)
  int* bcnt  = bz;
  int* bcur  = bz + nbuck;
  int* off   = (int*)alloc((size_t)(N+1)*4);
  int* csr   = (int*)alloc((size_t)E*4);
  unsigned* ebuf = (unsigned*)alloc((size_t)E*4);
  unsigned* xb   = (unsigned*)alloc((size_t)N*64*4);
  unsigned* h_a  = (unsigned*)alloc((size_t)N*64*4);
  unsigned* h_b  = (unsigned*)alloc((size_t)N*64*4);
  unsigned* ylb  = (unsigned*)alloc((size_t)N*32*4);
  unsigned short* Bpk0 = (unsigned short*)alloc((size_t)256*dout[0]*2);
  unsigned short* Bpk1 = (unsigned short*)alloc((size_t)256*dout[1]*2);
  unsigned short* BpkL = (unsigned short*)alloc((size_t)128*dout[2]*2);
  unsigned short* BpkR = (unsigned short*)alloc((size_t)128*dout[2]*2);
  float* sc[3]; float* sh[3];
  for (int i=0;i<3;i++){
    sc[i] = (float*)alloc((size_t)dout[i]*4);
    sh[i] = (float*)alloc((size_t)dout[i]*4);
  }

  hipMemsetAsync(bz, 0, (size_t)2*nbuck*4, stream);

  WtpArgs wa[4];
  wa[0] = { Wl[0], Wr[0], bl[0], g[0], bb[0], rm[0], rv[0], Bpk0, sc[0], sh[0], 8, dout[0], 1, CDIV(256*dout[0]+dout[0],256) };
  wa[1] = { Wl[1], Wr[1], bl[1], g[1], bb[1], rm[1], rv[1], Bpk1, sc[1], sh[1], 8, dout[1], 1, CDIV(256*dout[1]+dout[1],256) };
  wa[2] = { Wl[2], nullptr, nullptr, nullptr, nullptr, nullptr, nullptr, BpkL, nullptr, nullptr, 4, dout[2], 0, CDIV(128*dout[2],256) };
  wa[3] = { Wr[2], nullptr, bl[2], g[2], bb[2], rm[2], rv[2], BpkR, sc[2], sh[2], 4, dout[2], 1, CDIV(128*dout[2]+dout[2],256) };

  int castBlocks = CDIV(N*64, 256);
  int histBlocks = CDIV(E, 256*16);
  int prepBlocks = castBlocks + histBlocks + wa[0].nblk + wa[1].nblk + wa[2].nblk + wa[3].nblk;
  k_prep   <<<prepBlocks,256,0,stream>>>(x, N*64, xb, edst, E, bcnt, nbuck, castBlocks, histBlocks,
                                         wa[0], wa[1], wa[2], wa[3]);
  k_bucketA<<<CDIV(E,256*16),256,0,stream>>>(esrc, edst, E, bcnt, bcur, ebuf, nbuck);
  k_bucketB<<<nbuck,256,0,stream>>>(ebuf, bcnt, N, off, csr, nbuck);

  int tileGrid = CDIV(N, 64);
  // layer 0: fused gather + dual-K GEMM
  k_fused<false><<<tileGrid,256,0,stream>>>((const unsigned short*)xb, off, csr,
                                            Bpk0, sc[0], sh[0], nullptr,
                                            (unsigned short*)h_a, nullptr, N);
  // layer 1: fused gather + dual-K GEMM + yl mini-GEMM
  k_fused<true><<<tileGrid,256,0,stream>>>((const unsigned short*)h_a, off, csr,
                                           Bpk1, sc[1], sh[1], BpkL,
                                           (unsigned short*)h_b, (unsigned short*)ylb, N);
  // layer 2: fused mean-yl gather + final GEMM + BN + L2norm
  k_aggf<<<tileGrid,256,0,stream>>>((const uint4*)ylb, off, csr,
                                    (const unsigned short*)h_b, BpkR, sc[2], sh[2],
                                    (float*)d_out, N);
}